// Round 2
// baseline (1132.328 us; speedup 1.0000x reference)
//
#include <hip/hip_runtime.h>

typedef unsigned short u16;
typedef short s16x8 __attribute__((ext_vector_type(8)));
typedef float f32x4 __attribute__((ext_vector_type(4)));
typedef float f32x2 __attribute__((ext_vector_type(2)));

#define B_ 64
#define Hh 28
#define Ww 28
#define Cc 384
#define Gg 7
#define Nn 49
#define NH 12
#define HD 32
#define TT 50176            // B*H*W tokens
#define NWIN 1024           // B * 16 windows
#define QKV_ELEMS 19267584u // 1024*12*49*32 per q/k/v
#define SCALE_Q 0.17677669529663687f

__device__ __forceinline__ float b2f(u16 u) {
  union { unsigned int i; float f; } v; v.i = ((unsigned int)u) << 16; return v.f;
}
__device__ __forceinline__ u16 f2b(float f) {
  union { float f; unsigned int i; } v; v.f = f;
  unsigned int r = v.i + 0x7fffu + ((v.i >> 16) & 1u);
  return (u16)(r >> 16);
}

// ------------- transpose + fp32->bf16 cast: in[K][N] fp32 -> out[N][K] bf16 -------------
__global__ void transpose_f2b(const float* __restrict__ in, u16* __restrict__ out,
                              int K, int N) {
  int i = blockIdx.x * 256 + threadIdx.x;
  if (i < K * N) {
    int k = i / N, n = i % N;
    out[(size_t)n * K + k] = f2b(in[i]);
  }
}

// ---------------- dynamic position bias MLP (169 rows), fp32 in/out ----------------
__global__ __launch_bounds__(256)
void pos_mlp_kernel(const float* __restrict__ pp_w, const float* __restrict__ pp_b,
                    const float* __restrict__ l1g, const float* __restrict__ l1b,
                    const float* __restrict__ p1w, const float* __restrict__ p1b,
                    const float* __restrict__ l2g, const float* __restrict__ l2b,
                    const float* __restrict__ p2w, const float* __restrict__ p2b,
                    const float* __restrict__ l3g, const float* __restrict__ l3b,
                    const float* __restrict__ p3w, const float* __restrict__ p3b,
                    float* __restrict__ pos169) {
  __shared__ float w0[48], bb0[24], g1[24], e1[24], w1[576], bb1[24],
                   g2[24], e2[24], w2[576], bb2[24], g3[24], e3[24], w3[288], bb3[12];
  int tid = threadIdx.x;
  for (int i = tid; i < 48; i += 256) w0[i] = pp_w[i];
  for (int i = tid; i < 24; i += 256) {
    bb0[i] = pp_b[i]; g1[i] = l1g[i]; e1[i] = l1b[i]; bb1[i] = p1b[i];
    g2[i] = l2g[i]; e2[i] = l2b[i]; bb2[i] = p2b[i];
    g3[i] = l3g[i]; e3[i] = l3b[i];
  }
  for (int i = tid; i < 576; i += 256) { w1[i] = p1w[i]; w2[i] = p2w[i]; }
  for (int i = tid; i < 288; i += 256) w3[i] = p3w[i];
  for (int i = tid; i < 12; i += 256) bb3[i] = p3b[i];
  __syncthreads();
  if (tid < 169) {
    float bi = (float)(tid / 13) - 6.f, bj = (float)(tid % 13) - 6.f;
    float cur[24], t[24];
    #pragma unroll
    for (int c = 0; c < 24; c++) cur[c] = bi * w0[c] + bj * w0[24 + c] + bb0[c];

    auto lnrelu = [&](const float* gg, const float* ee) {
      float s = 0.f, sq = 0.f;
      #pragma unroll
      for (int c = 0; c < 24; c++) { s += cur[c]; sq += cur[c] * cur[c]; }
      float mean = s * (1.f / 24.f);
      float var = sq * (1.f / 24.f) - mean * mean;
      float rstd = rsqrtf(var + 1e-5f);
      #pragma unroll
      for (int c = 0; c < 24; c++)
        t[c] = fmaxf(0.f, (cur[c] - mean) * rstd * gg[c] + ee[c]);
    };

    lnrelu(g1, e1);
    #pragma unroll
    for (int o = 0; o < 24; o++) {
      float a = bb1[o];
      #pragma unroll
      for (int c = 0; c < 24; c++) a += t[c] * w1[c * 24 + o];
      cur[o] = a;
    }
    lnrelu(g2, e2);
    #pragma unroll
    for (int o = 0; o < 24; o++) {
      float a = bb2[o];
      #pragma unroll
      for (int c = 0; c < 24; c++) a += t[c] * w2[c * 24 + o];
      cur[o] = a;
    }
    lnrelu(g3, e3);
    #pragma unroll
    for (int h = 0; h < 12; h++) {
      float a = bb3[h];
      #pragma unroll
      for (int c = 0; c < 24; c++) a += t[c] * w3[c * 12 + h];
      pos169[tid * 12 + h] = a;
    }
  }
}

// ------------- LayerNorm over C=384: fp32 in -> bf16 out, one wave per row -------------
__global__ __launch_bounds__(256)
void ln_kernel(const float* __restrict__ x, const float* __restrict__ g,
               const float* __restrict__ be, u16* __restrict__ out) {
  int wid = threadIdx.x >> 6, lane = threadIdx.x & 63;
  size_t row = (size_t)blockIdx.x * 4 + wid;
  const float* xr = x + row * Cc;
  float v[6];
  float s = 0.f, sq = 0.f;
  #pragma unroll
  for (int p = 0; p < 3; p++) {
    f32x2 u = *(const f32x2*)&xr[p * 128 + lane * 2];
    v[2 * p] = u.x; v[2 * p + 1] = u.y;
    s += u.x + u.y; sq += u.x * u.x + u.y * u.y;
  }
  #pragma unroll
  for (int off = 32; off > 0; off >>= 1) { s += __shfl_xor(s, off); sq += __shfl_xor(sq, off); }
  float mean = s * (1.f / 384.f);
  float var = sq * (1.f / 384.f) - mean * mean;
  float rstd = rsqrtf(var + 1e-5f);
  u16* orow = out + row * Cc;
  #pragma unroll
  for (int p = 0; p < 3; p++) {
    int c = p * 128 + lane * 2;
    f32x2 ug = *(const f32x2*)&g[c];
    f32x2 ub = *(const f32x2*)&be[c];
    float o0 = (v[2 * p] - mean) * rstd * ug.x + ub.x;
    float o1 = (v[2 * p + 1] - mean) * rstd * ug.y + ub.y;
    unsigned int uo = (unsigned int)f2b(o0) | ((unsigned int)f2b(o1) << 16);
    *(unsigned int*)&orow[c] = uo;
  }
}

// ---------------- MFMA GEMM: C[M][N] = A[M][K] * Bt[N][K]^T, 128x128 tile ----------------
// EPI 0: qkv scatter (+bias, q*SCALE) into [3][1024][12][49][32] bf16
// EPI 1: +bias +res(fp32), store fp32 (proj / fc2 residual)
// EPI 2: +bias, exact GELU, store bf16 [row*1536+col]
template <int EPI>
__global__ __launch_bounds__(256, 2)
void gemm_k(const u16* __restrict__ A, const u16* __restrict__ Bt,
            const float* __restrict__ bias, const void* resv, void* outv,
            int M, int N, int K, int rowoff) {
  __shared__ u16 As[128 * 40];
  __shared__ u16 Bs[128 * 40];
  const int tid = threadIdx.x;
  const int mBase = blockIdx.y * 128;
  const int nBase = blockIdx.x * 128;
  const int wid = tid >> 6, lane = tid & 63;
  const int wr = (wid >> 1) * 64, wc = (wid & 1) * 64;
  const int lm = lane & 15, lq = lane >> 4;

  f32x4 acc[4][4] = {};
  for (int k0 = 0; k0 < K; k0 += 32) {
    #pragma unroll
    for (int ss = 0; ss < 2; ss++) {
      int li = tid + ss * 256;      // 0..511
      int r = li >> 2, c8 = (li & 3) * 8;
      *(s16x8*)&As[r * 40 + c8] = *(const s16x8*)&A[(size_t)(mBase + r) * K + k0 + c8];
      *(s16x8*)&Bs[r * 40 + c8] = *(const s16x8*)&Bt[(size_t)(nBase + r) * K + k0 + c8];
    }
    __syncthreads();
    s16x8 af[4], bfr[4];
    #pragma unroll
    for (int i = 0; i < 4; i++) af[i] = *(const s16x8*)&As[(wr + i * 16 + lm) * 40 + lq * 8];
    #pragma unroll
    for (int j = 0; j < 4; j++) bfr[j] = *(const s16x8*)&Bs[(wc + j * 16 + lm) * 40 + lq * 8];
    #pragma unroll
    for (int i = 0; i < 4; i++)
      #pragma unroll
      for (int j = 0; j < 4; j++)
        acc[i][j] = __builtin_amdgcn_mfma_f32_16x16x32_bf16(af[i], bfr[j], acc[i][j], 0, 0, 0);
    __syncthreads();
  }

  int colA[4]; float bvv[4];
  #pragma unroll
  for (int j = 0; j < 4; j++) {
    colA[j] = nBase + wc + j * 16 + lm;
    bvv[j] = bias[colA[j]];
  }

  if constexpr (EPI == 0) {
    u16* out = (u16*)outv;
    size_t offj[4]; float scl[4];
    #pragma unroll
    for (int j = 0; j < 4; j++) {
      int col = colA[j];
      int qi = col / 384, c2 = col % 384;
      int head = c2 >> 5, d = c2 & 31;
      offj[j] = (size_t)qi * QKV_ELEMS + (size_t)head * 1568 + d;
      scl[j] = (qi == 0) ? SCALE_Q : 1.0f;
    }
    #pragma unroll
    for (int i = 0; i < 4; i++) {
      #pragma unroll
      for (int rg = 0; rg < 4; rg++) {
        int t = mBase + wr + i * 16 + lq * 4 + rg;
        int b_ = t / 784, rr = t % 784;
        int hh = rr / 28, ww = rr % 28;
        int widx = b_ * 16 + (hh / 7) * 4 + (ww / 7);
        int n = (hh % 7) * 7 + (ww % 7);
        size_t offr = (size_t)widx * 18816 + n * 32;
        #pragma unroll
        for (int j = 0; j < 4; j++)
          out[offj[j] + offr] = f2b((acc[i][j][rg] + bvv[j]) * scl[j]);
      }
    }
  } else if constexpr (EPI == 1) {
    float* out = (float*)outv;
    const float* res = (const float*)resv;
    #pragma unroll
    for (int i = 0; i < 4; i++) {
      #pragma unroll
      for (int rg = 0; rg < 4; rg++) {
        size_t rb = (size_t)(rowoff + mBase + wr + i * 16 + lq * 4 + rg) * 384;
        #pragma unroll
        for (int j = 0; j < 4; j++) {
          size_t o = rb + colA[j];
          out[o] = acc[i][j][rg] + bvv[j] + res[o];
        }
      }
    }
  } else {  // EPI == 2: GELU -> bf16
    u16* out = (u16*)outv;
    #pragma unroll
    for (int i = 0; i < 4; i++) {
      #pragma unroll
      for (int rg = 0; rg < 4; rg++) {
        size_t rb = (size_t)(mBase + wr + i * 16 + lq * 4 + rg) * 1536;
        #pragma unroll
        for (int j = 0; j < 4; j++) {
          float v = acc[i][j][rg] + bvv[j];
          float gl = 0.5f * v * (1.0f + erff(v * 0.70710678118654752f));
          out[rb + colA[j]] = f2b(gl);
        }
      }
    }
  }
}

// ---------------- attention: one wave per (window, head) ----------------
__global__ __launch_bounds__(64)
void attn_kernel(const u16* __restrict__ qkv, const float* __restrict__ pos169,
                 u16* __restrict__ attn_out) {
  __shared__ float q_l[49 * 36];
  __shared__ float v_l[49 * 33];
  __shared__ float s_l[49 * 52];
  __shared__ float bias_l[169];
  int lane = threadIdx.x;
  int widx = blockIdx.x / 12, head = blockIdx.x % 12;
  size_t base = (size_t)widx * 18816 + (size_t)head * 1568;
  const u16* qp = qkv + base;
  const u16* kp = qkv + QKV_ELEMS + base;
  const u16* vp = qkv + 2u * QKV_ELEMS + base;

  for (int i = lane; i < 169; i += 64) bias_l[i] = pos169[i * 12 + head];
  for (int i = lane; i < 1568; i += 64) {
    int nn = i >> 5, dd = i & 31;
    q_l[nn * 36 + dd] = b2f(qp[i]);
    v_l[nn * 33 + dd] = b2f(vp[i]);
  }
  float kr[32];
  if (lane < 49) {
    #pragma unroll
    for (int ii = 0; ii < 32; ii++) kr[ii] = b2f(kp[lane * 32 + ii]);
  }
  int mh = lane / 7, mw = lane % 7;
  __syncthreads();

  for (int n = 0; n < 49; n++) {
    float dot;
    if (lane < 49) {
      dot = 0.f;
      #pragma unroll
      for (int i4 = 0; i4 < 8; i4++) {
        f32x4 qv = *(const f32x4*)&q_l[n * 36 + i4 * 4];
        dot += qv.x * kr[i4 * 4 + 0] + qv.y * kr[i4 * 4 + 1] +
               qv.z * kr[i4 * 4 + 2] + qv.w * kr[i4 * 4 + 3];
      }
      dot += bias_l[(n / 7 - mh + 6) * 13 + (n % 7 - mw + 6)];
    } else {
      dot = -1e30f;
    }
    float mx = dot;
    #pragma unroll
    for (int off = 32; off > 0; off >>= 1) mx = fmaxf(mx, __shfl_xor(mx, off));
    float p = (lane < 49) ? __expf(dot - mx) : 0.f;
    float sm = p;
    #pragma unroll
    for (int off = 32; off > 0; off >>= 1) sm += __shfl_xor(sm, off);
    if (lane < 49) s_l[lane * 52 + n] = p / sm;
  }
  for (int i = lane; i < 49; i += 64) {
    s_l[i * 52 + 49] = 0.f; s_l[i * 52 + 50] = 0.f; s_l[i * 52 + 51] = 0.f;
  }
  __syncthreads();

  int d = lane & 31, hw = lane >> 5;
  float av[7][4] = {};
  for (int m = 0; m < 49; m++) {
    float vv = v_l[m * 33 + d];
    #pragma unroll
    for (int gi = 0; gi < 7; gi++) {
      int g = hw + 2 * gi;
      if (g < 13) {
        f32x4 pv = *(const f32x4*)&s_l[m * 52 + g * 4];
        av[gi][0] += pv.x * vv; av[gi][1] += pv.y * vv;
        av[gi][2] += pv.z * vv; av[gi][3] += pv.w * vv;
      }
    }
  }
  int b_ = widx >> 4, wq = widx & 15;
  #pragma unroll
  for (int gi = 0; gi < 7; gi++) {
    int g = hw + 2 * gi;
    #pragma unroll
    for (int jj = 0; jj < 4; jj++) {
      int n = g * 4 + jj;
      if (g < 13 && n < 49) {
        int hh = (wq >> 2) * 7 + n / 7, ww2 = (wq & 3) * 7 + n % 7;
        int t = b_ * 784 + hh * 28 + ww2;
        attn_out[(size_t)t * 384 + head * 32 + d] = f2b(av[gi][jj]);
      }
    }
  }
}

extern "C" void kernel_launch(void* const* d_in, const int* in_sizes, int n_in,
                              void* d_out, int out_size, void* d_ws, size_t ws_size,
                              hipStream_t stream) {
  const float* x      = (const float*)d_in[0];
  const float* n1g    = (const float*)d_in[1];
  const float* n1b    = (const float*)d_in[2];
  const float* qkv_w  = (const float*)d_in[3];
  const float* qkv_b  = (const float*)d_in[4];
  const float* proj_w = (const float*)d_in[5];
  const float* proj_b = (const float*)d_in[6];
  const float* n2g    = (const float*)d_in[7];
  const float* n2b    = (const float*)d_in[8];
  const float* fc1_w  = (const float*)d_in[9];
  const float* fc1_b  = (const float*)d_in[10];
  const float* fc2_w  = (const float*)d_in[11];
  const float* fc2_b  = (const float*)d_in[12];

  // ws layout (bytes)
  const size_t SZ_A = 115605504;   // qkv (3*1024*12*49*32 bf16) / MLP hidden chunks
  const size_t SZ_B = 38535168;    // h (LN out) / attn_out / h2 (bf16)
  char* wsb = (char*)d_ws;
  u16* regA     = (u16*)wsb;
  u16* regB     = (u16*)(wsb + SZ_A);
  float* pos169 = (float*)(wsb + SZ_A + SZ_B);
  u16* qkvT     = (u16*)(wsb + SZ_A + SZ_B + 8192);
  u16* projT    = qkvT + 442368;
  u16* fc1T     = projT + 147456;
  u16* fc2T     = fc1T + 589824;

  float* out = (float*)d_out;

  // weight transposes [K][N] fp32 -> [N][K] bf16
  transpose_f2b<<<1728, 256, 0, stream>>>(qkv_w, qkvT, 384, 1152);
  transpose_f2b<<<576, 256, 0, stream>>>(proj_w, projT, 384, 384);
  transpose_f2b<<<2304, 256, 0, stream>>>(fc1_w, fc1T, 384, 1536);
  transpose_f2b<<<2304, 256, 0, stream>>>(fc2_w, fc2T, 1536, 384);

  // dynamic position bias table [169][12] fp32
  pos_mlp_kernel<<<1, 256, 0, stream>>>(
      (const float*)d_in[13], (const float*)d_in[14], (const float*)d_in[15], (const float*)d_in[16],
      (const float*)d_in[17], (const float*)d_in[18], (const float*)d_in[19], (const float*)d_in[20],
      (const float*)d_in[21], (const float*)d_in[22], (const float*)d_in[23], (const float*)d_in[24],
      (const float*)d_in[25], (const float*)d_in[26], pos169);

  // LN1: x(fp32) -> regB(bf16)
  ln_kernel<<<TT / 4, 256, 0, stream>>>(x, n1g, n1b, regB);

  // QKV GEMM with window scatter: regB -> regA (bf16)
  gemm_k<0><<<dim3(9, 392), 256, 0, stream>>>(regB, qkvT, qkv_b, nullptr, regA,
                                              TT, 1152, 384, 0);

  // attention: regA -> regB (attn_out bf16, token order)
  attn_kernel<<<NWIN * NH, 64, 0, stream>>>(regA, pos169, regB);

  // proj + residual(x fp32): regB -> d_out (fp32 x2)
  gemm_k<1><<<dim3(3, 392), 256, 0, stream>>>(regB, projT, proj_b, x, out,
                                              TT, 384, 384, 0);

  // LN2: d_out(fp32) -> regB(bf16)
  ln_kernel<<<TT / 4, 256, 0, stream>>>(out, n2g, n2b, regB);

  // MLP in 2 row-chunks of 25088 (hidden bf16 reuses regA)
  for (int ch = 0; ch < 2; ch++) {
    const u16* h2c = regB + (size_t)ch * 25088 * 384;
    gemm_k<2><<<dim3(12, 196), 256, 0, stream>>>(h2c, fc1T, fc1_b, nullptr, regA,
                                                 25088, 1536, 384, 0);
    gemm_k<1><<<dim3(3, 196), 256, 0, stream>>>(regA, fc2T, fc2_b, out, out,
                                                25088, 384, 1536, ch * 25088);
  }
}

// Round 3
// 765.506 us; speedup vs baseline: 1.4792x; 1.4792x over previous
//
#include <hip/hip_runtime.h>

typedef unsigned short u16;
typedef short s16x8 __attribute__((ext_vector_type(8)));
typedef short s16x4 __attribute__((ext_vector_type(4)));
typedef float f32x4 __attribute__((ext_vector_type(4)));
typedef float f32x2 __attribute__((ext_vector_type(2)));

#define B_ 64
#define Hh 28
#define Ww 28
#define Cc 384
#define Gg 7
#define Nn 49
#define NH 12
#define HD 32
#define TT 50176            // B*H*W tokens
#define NWIN 1024           // B * 16 windows
#define QKV_ELEMS 19267584u // 1024*12*49*32 per q/k/v
#define SCALE_Q 0.17677669529663687f

__device__ __forceinline__ float b2f(u16 u) {
  union { unsigned int i; float f; } v; v.i = ((unsigned int)u) << 16; return v.f;
}
__device__ __forceinline__ u16 f2b(float f) {
  union { float f; unsigned int i; } v; v.f = f;
  unsigned int r = v.i + 0x7fffu + ((v.i >> 16) & 1u);
  return (u16)(r >> 16);
}

// ------------- transpose + fp32->bf16 cast: in[K][N] fp32 -> out[N][K] bf16 -------------
__global__ void transpose_f2b(const float* __restrict__ in, u16* __restrict__ out,
                              int K, int N) {
  int i = blockIdx.x * 256 + threadIdx.x;
  if (i < K * N) {
    int k = i / N, n = i % N;
    out[(size_t)n * K + k] = f2b(in[i]);
  }
}

// ---------------- dynamic position bias MLP (169 rows), fp32 in/out ----------------
__global__ __launch_bounds__(256)
void pos_mlp_kernel(const float* __restrict__ pp_w, const float* __restrict__ pp_b,
                    const float* __restrict__ l1g, const float* __restrict__ l1b,
                    const float* __restrict__ p1w, const float* __restrict__ p1b,
                    const float* __restrict__ l2g, const float* __restrict__ l2b,
                    const float* __restrict__ p2w, const float* __restrict__ p2b,
                    const float* __restrict__ l3g, const float* __restrict__ l3b,
                    const float* __restrict__ p3w, const float* __restrict__ p3b,
                    float* __restrict__ pos169) {
  __shared__ float w0[48], bb0[24], g1[24], e1[24], w1[576], bb1[24],
                   g2[24], e2[24], w2[576], bb2[24], g3[24], e3[24], w3[288], bb3[12];
  int tid = threadIdx.x;
  for (int i = tid; i < 48; i += 256) w0[i] = pp_w[i];
  for (int i = tid; i < 24; i += 256) {
    bb0[i] = pp_b[i]; g1[i] = l1g[i]; e1[i] = l1b[i]; bb1[i] = p1b[i];
    g2[i] = l2g[i]; e2[i] = l2b[i]; bb2[i] = p2b[i];
    g3[i] = l3g[i]; e3[i] = l3b[i];
  }
  for (int i = tid; i < 576; i += 256) { w1[i] = p1w[i]; w2[i] = p2w[i]; }
  for (int i = tid; i < 288; i += 256) w3[i] = p3w[i];
  for (int i = tid; i < 12; i += 256) bb3[i] = p3b[i];
  __syncthreads();
  if (tid < 169) {
    float bi = (float)(tid / 13) - 6.f, bj = (float)(tid % 13) - 6.f;
    float cur[24], t[24];
    #pragma unroll
    for (int c = 0; c < 24; c++) cur[c] = bi * w0[c] + bj * w0[24 + c] + bb0[c];

    auto lnrelu = [&](const float* gg, const float* ee) {
      float s = 0.f, sq = 0.f;
      #pragma unroll
      for (int c = 0; c < 24; c++) { s += cur[c]; sq += cur[c] * cur[c]; }
      float mean = s * (1.f / 24.f);
      float var = sq * (1.f / 24.f) - mean * mean;
      float rstd = rsqrtf(var + 1e-5f);
      #pragma unroll
      for (int c = 0; c < 24; c++)
        t[c] = fmaxf(0.f, (cur[c] - mean) * rstd * gg[c] + ee[c]);
    };

    lnrelu(g1, e1);
    #pragma unroll
    for (int o = 0; o < 24; o++) {
      float a = bb1[o];
      #pragma unroll
      for (int c = 0; c < 24; c++) a += t[c] * w1[c * 24 + o];
      cur[o] = a;
    }
    lnrelu(g2, e2);
    #pragma unroll
    for (int o = 0; o < 24; o++) {
      float a = bb2[o];
      #pragma unroll
      for (int c = 0; c < 24; c++) a += t[c] * w2[c * 24 + o];
      cur[o] = a;
    }
    lnrelu(g3, e3);
    #pragma unroll
    for (int h = 0; h < 12; h++) {
      float a = bb3[h];
      #pragma unroll
      for (int c = 0; c < 24; c++) a += t[c] * w3[c * 12 + h];
      pos169[tid * 12 + h] = a;
    }
  }
}

// ------------- LayerNorm over C=384: fp32 in -> bf16 out, one wave per row -------------
__global__ __launch_bounds__(256)
void ln_kernel(const float* __restrict__ x, const float* __restrict__ g,
               const float* __restrict__ be, u16* __restrict__ out) {
  int wid = threadIdx.x >> 6, lane = threadIdx.x & 63;
  size_t row = (size_t)blockIdx.x * 4 + wid;
  const float* xr = x + row * Cc;
  float v[6];
  float s = 0.f, sq = 0.f;
  #pragma unroll
  for (int p = 0; p < 3; p++) {
    f32x2 u = *(const f32x2*)&xr[p * 128 + lane * 2];
    v[2 * p] = u.x; v[2 * p + 1] = u.y;
    s += u.x + u.y; sq += u.x * u.x + u.y * u.y;
  }
  #pragma unroll
  for (int off = 32; off > 0; off >>= 1) { s += __shfl_xor(s, off); sq += __shfl_xor(sq, off); }
  float mean = s * (1.f / 384.f);
  float var = sq * (1.f / 384.f) - mean * mean;
  float rstd = rsqrtf(var + 1e-5f);
  u16* orow = out + row * Cc;
  #pragma unroll
  for (int p = 0; p < 3; p++) {
    int c = p * 128 + lane * 2;
    f32x2 ug = *(const f32x2*)&g[c];
    f32x2 ub = *(const f32x2*)&be[c];
    float o0 = (v[2 * p] - mean) * rstd * ug.x + ub.x;
    float o1 = (v[2 * p + 1] - mean) * rstd * ug.y + ub.y;
    unsigned int uo = (unsigned int)f2b(o0) | ((unsigned int)f2b(o1) << 16);
    *(unsigned int*)&orow[c] = uo;
  }
}

// ---------------- MFMA GEMM: C[M][N] = A[M][K] * Bt[N][K]^T, 128x128 tile ----------------
// EPI 0: qkv scatter (+bias, q*SCALE) into [3][1024][12][49][32] bf16
// EPI 1: +bias +res(fp32), store fp32 (proj / fc2 residual)
// EPI 2: +bias, exact GELU, store bf16 [row*1536+col]
template <int EPI>
__global__ __launch_bounds__(256, 2)
void gemm_k(const u16* __restrict__ A, const u16* __restrict__ Bt,
            const float* __restrict__ bias, const void* resv, void* outv,
            int M, int N, int K, int rowoff) {
  __shared__ u16 As[128 * 40];
  __shared__ u16 Bs[128 * 40];
  const int tid = threadIdx.x;
  const int mBase = blockIdx.y * 128;
  const int nBase = blockIdx.x * 128;
  const int wid = tid >> 6, lane = tid & 63;
  const int wr = (wid >> 1) * 64, wc = (wid & 1) * 64;
  const int lm = lane & 15, lq = lane >> 4;

  f32x4 acc[4][4] = {};
  for (int k0 = 0; k0 < K; k0 += 32) {
    #pragma unroll
    for (int ss = 0; ss < 2; ss++) {
      int li = tid + ss * 256;      // 0..511
      int r = li >> 2, c8 = (li & 3) * 8;
      *(s16x8*)&As[r * 40 + c8] = *(const s16x8*)&A[(size_t)(mBase + r) * K + k0 + c8];
      *(s16x8*)&Bs[r * 40 + c8] = *(const s16x8*)&Bt[(size_t)(nBase + r) * K + k0 + c8];
    }
    __syncthreads();
    s16x8 af[4], bfr[4];
    #pragma unroll
    for (int i = 0; i < 4; i++) af[i] = *(const s16x8*)&As[(wr + i * 16 + lm) * 40 + lq * 8];
    #pragma unroll
    for (int j = 0; j < 4; j++) bfr[j] = *(const s16x8*)&Bs[(wc + j * 16 + lm) * 40 + lq * 8];
    #pragma unroll
    for (int i = 0; i < 4; i++)
      #pragma unroll
      for (int j = 0; j < 4; j++)
        acc[i][j] = __builtin_amdgcn_mfma_f32_16x16x32_bf16(af[i], bfr[j], acc[i][j], 0, 0, 0);
    __syncthreads();
  }

  int colA[4]; float bvv[4];
  #pragma unroll
  for (int j = 0; j < 4; j++) {
    colA[j] = nBase + wc + j * 16 + lm;
    bvv[j] = bias[colA[j]];
  }

  if constexpr (EPI == 0) {
    u16* out = (u16*)outv;
    size_t offj[4]; float scl[4];
    #pragma unroll
    for (int j = 0; j < 4; j++) {
      int col = colA[j];
      int qi = col / 384, c2 = col % 384;
      int head = c2 >> 5, d = c2 & 31;
      offj[j] = (size_t)qi * QKV_ELEMS + (size_t)head * 1568 + d;
      scl[j] = (qi == 0) ? SCALE_Q : 1.0f;
    }
    #pragma unroll
    for (int i = 0; i < 4; i++) {
      #pragma unroll
      for (int rg = 0; rg < 4; rg++) {
        int t = mBase + wr + i * 16 + lq * 4 + rg;
        int b_ = t / 784, rr = t % 784;
        int hh = rr / 28, ww = rr % 28;
        int widx = b_ * 16 + (hh / 7) * 4 + (ww / 7);
        int n = (hh % 7) * 7 + (ww % 7);
        size_t offr = (size_t)widx * 18816 + n * 32;
        #pragma unroll
        for (int j = 0; j < 4; j++)
          out[offj[j] + offr] = f2b((acc[i][j][rg] + bvv[j]) * scl[j]);
      }
    }
  } else if constexpr (EPI == 1) {
    float* out = (float*)outv;
    const float* res = (const float*)resv;
    #pragma unroll
    for (int i = 0; i < 4; i++) {
      #pragma unroll
      for (int rg = 0; rg < 4; rg++) {
        size_t rb = (size_t)(rowoff + mBase + wr + i * 16 + lq * 4 + rg) * 384;
        #pragma unroll
        for (int j = 0; j < 4; j++) {
          size_t o = rb + colA[j];
          out[o] = acc[i][j][rg] + bvv[j] + res[o];
        }
      }
    }
  } else {  // EPI == 2: GELU -> bf16
    u16* out = (u16*)outv;
    #pragma unroll
    for (int i = 0; i < 4; i++) {
      #pragma unroll
      for (int rg = 0; rg < 4; rg++) {
        size_t rb = (size_t)(mBase + wr + i * 16 + lq * 4 + rg) * 1536;
        #pragma unroll
        for (int j = 0; j < 4; j++) {
          float v = acc[i][j][rg] + bvv[j];
          float gl = 0.5f * v * (1.0f + erff(v * 0.70710678118654752f));
          out[rb + colA[j]] = f2b(gl);
        }
      }
    }
  }
}

// ---------------- MFMA attention: one wave per (window, head), 4 waves/block ----------------
__global__ __launch_bounds__(256, 3)
void attn_mfma(const u16* __restrict__ qkv, const float* __restrict__ pos169,
               u16* __restrict__ attn_out) {
  __shared__ u16 P_l[4][64 * 68];     // per-wave P matrix, stride 68 (writes 2-way free)
  __shared__ float bias_l[4][170];
  const int wid = threadIdx.x >> 6, lane = threadIdx.x & 63;
  const int lm = lane & 15, lq = lane >> 4;
  const int pair = blockIdx.x * 4 + wid;
  const int widx = pair / 12, head = pair % 12;
  const u16* qp = qkv + (size_t)widx * 18816 + head * 1568;
  const u16* kp = qp + QKV_ELEMS;
  const u16* vp = kp + QKV_ELEMS;

  for (int i = lane; i < 169; i += 64) bias_l[wid][i] = pos169[i * 12 + head];

  // Q (A-op) and K (B-op) fragments straight from global: lane holds 8 contiguous d.
  s16x8 aq[4], bk[4];
  #pragma unroll
  for (int i = 0; i < 4; i++) aq[i] = *(const s16x8*)&qp[(i * 16 + lm) * 32 + lq * 8];
  #pragma unroll
  for (int j = 0; j < 4; j++) bk[j] = *(const s16x8*)&kp[(j * 16 + lm) * 32 + lq * 8];

  // scores: acc[i][j], row n = i*16+lq*4+rg, col m = j*16+lm   (K=32 in one step)
  f32x4 acc[4][4] = {};
  #pragma unroll
  for (int i = 0; i < 4; i++)
    #pragma unroll
    for (int j = 0; j < 4; j++)
      acc[i][j] = __builtin_amdgcn_mfma_f32_16x16x32_bf16(aq[i], bk[j], acc[i][j], 0, 0, 0);

  // per-column (m) constants
  int mj[4], mhj[4], mwj[4];
  #pragma unroll
  for (int j = 0; j < 4; j++) {
    mj[j] = j * 16 + lm; mhj[j] = mj[j] / 7; mwj[j] = mj[j] - mhj[j] * 7;
  }

  // bias + mask + softmax (row n spans 4 j-regs x 16 lanes of same lq group)
  #pragma unroll
  for (int i = 0; i < 4; i++) {
    #pragma unroll
    for (int rg = 0; rg < 4; rg++) {
      int n = i * 16 + lq * 4 + rg;
      int nh = n / 7, nw = n - nh * 7;
      float s[4];
      #pragma unroll
      for (int j = 0; j < 4; j++) {
        int idx = (nh - mhj[j] + 6) * 13 + (nw - mwj[j] + 6);
        idx = min(max(idx, 0), 168);
        s[j] = acc[i][j][rg] + bias_l[wid][idx];
        if (mj[j] >= 49) s[j] = -3.0e30f;
      }
      float mx = fmaxf(fmaxf(s[0], s[1]), fmaxf(s[2], s[3]));
      #pragma unroll
      for (int off = 1; off < 16; off <<= 1) mx = fmaxf(mx, __shfl_xor(mx, off));
      float e[4];
      float sm = 0.f;
      #pragma unroll
      for (int j = 0; j < 4; j++) { e[j] = __expf(s[j] - mx); sm += e[j]; }
      #pragma unroll
      for (int off = 1; off < 16; off <<= 1) sm += __shfl_xor(sm, off);
      float r = 1.0f / sm;
      #pragma unroll
      for (int j = 0; j < 4; j++)
        P_l[wid][n * 68 + mj[j]] = f2b(e[j] * r);
    }
  }

  // PV: A = P from LDS (2x b64 per frag, 8B-aligned), B = V^T via strided global loads
  s16x8 ap[4][2];
  #pragma unroll
  for (int i = 0; i < 4; i++)
    #pragma unroll
    for (int ks = 0; ks < 2; ks++) {
      const u16* p = &P_l[wid][(i * 16 + lm) * 68 + ks * 32 + lq * 8];
      s16x4 lo = *(const s16x4*)p;
      s16x4 hi = *(const s16x4*)(p + 4);
      ap[i][ks] = __builtin_shufflevector(lo, hi, 0, 1, 2, 3, 4, 5, 6, 7);
    }
  s16x8 bv[2][2];
  #pragma unroll
  for (int jt = 0; jt < 2; jt++)
    #pragma unroll
    for (int ks = 0; ks < 2; ks++) {
      s16x8 v;
      #pragma unroll
      for (int jj = 0; jj < 8; jj++)
        v[jj] = (short)vp[(ks * 32 + lq * 8 + jj) * 32 + jt * 16 + lm];
      bv[jt][ks] = v;
    }

  f32x4 o[4][2] = {};
  #pragma unroll
  for (int i = 0; i < 4; i++)
    #pragma unroll
    for (int jt = 0; jt < 2; jt++)
      #pragma unroll
      for (int ks = 0; ks < 2; ks++)
        o[i][jt] = __builtin_amdgcn_mfma_f32_16x16x32_bf16(ap[i][ks], bv[jt][ks], o[i][jt], 0, 0, 0);

  // epilogue: row n = i*16+lq*4+rg, col d = jt*16+lm -> attn_out[t*384 + head*32 + d]
  const int b_ = widx >> 4, wq = widx & 15;
  const int hbase = (wq >> 2) * 7, wbase = (wq & 3) * 7;
  #pragma unroll
  for (int i = 0; i < 4; i++) {
    #pragma unroll
    for (int rg = 0; rg < 4; rg++) {
      int n = i * 16 + lq * 4 + rg;
      if (n < 49) {
        int nh = n / 7, nw = n - nh * 7;
        int t = b_ * 784 + (hbase + nh) * 28 + (wbase + nw);
        size_t ob = (size_t)t * 384 + head * 32 + lm;
        attn_out[ob] = f2b(o[i][0][rg]);
        attn_out[ob + 16] = f2b(o[i][1][rg]);
      }
    }
  }
}

extern "C" void kernel_launch(void* const* d_in, const int* in_sizes, int n_in,
                              void* d_out, int out_size, void* d_ws, size_t ws_size,
                              hipStream_t stream) {
  const float* x      = (const float*)d_in[0];
  const float* n1g    = (const float*)d_in[1];
  const float* n1b    = (const float*)d_in[2];
  const float* qkv_w  = (const float*)d_in[3];
  const float* qkv_b  = (const float*)d_in[4];
  const float* proj_w = (const float*)d_in[5];
  const float* proj_b = (const float*)d_in[6];
  const float* n2g    = (const float*)d_in[7];
  const float* n2b    = (const float*)d_in[8];
  const float* fc1_w  = (const float*)d_in[9];
  const float* fc1_b  = (const float*)d_in[10];
  const float* fc2_w  = (const float*)d_in[11];
  const float* fc2_b  = (const float*)d_in[12];

  // ws layout (bytes)
  const size_t SZ_A = 115605504;   // qkv (3*1024*12*49*32 bf16) / MLP hidden chunks
  const size_t SZ_B = 38535168;    // h (LN out) / attn_out / h2 (bf16)
  char* wsb = (char*)d_ws;
  u16* regA     = (u16*)wsb;
  u16* regB     = (u16*)(wsb + SZ_A);
  float* pos169 = (float*)(wsb + SZ_A + SZ_B);
  u16* qkvT     = (u16*)(wsb + SZ_A + SZ_B + 8192);
  u16* projT    = qkvT + 442368;
  u16* fc1T     = projT + 147456;
  u16* fc2T     = fc1T + 589824;

  float* out = (float*)d_out;

  // weight transposes [K][N] fp32 -> [N][K] bf16
  transpose_f2b<<<1728, 256, 0, stream>>>(qkv_w, qkvT, 384, 1152);
  transpose_f2b<<<576, 256, 0, stream>>>(proj_w, projT, 384, 384);
  transpose_f2b<<<2304, 256, 0, stream>>>(fc1_w, fc1T, 384, 1536);
  transpose_f2b<<<2304, 256, 0, stream>>>(fc2_w, fc2T, 1536, 384);

  // dynamic position bias table [169][12] fp32
  pos_mlp_kernel<<<1, 256, 0, stream>>>(
      (const float*)d_in[13], (const float*)d_in[14], (const float*)d_in[15], (const float*)d_in[16],
      (const float*)d_in[17], (const float*)d_in[18], (const float*)d_in[19], (const float*)d_in[20],
      (const float*)d_in[21], (const float*)d_in[22], (const float*)d_in[23], (const float*)d_in[24],
      (const float*)d_in[25], (const float*)d_in[26], pos169);

  // LN1: x(fp32) -> regB(bf16)
  ln_kernel<<<TT / 4, 256, 0, stream>>>(x, n1g, n1b, regB);

  // QKV GEMM with window scatter: regB -> regA (bf16)
  gemm_k<0><<<dim3(9, 392), 256, 0, stream>>>(regB, qkvT, qkv_b, nullptr, regA,
                                              TT, 1152, 384, 0);

  // attention (MFMA): regA -> regB (attn_out bf16, token order)
  attn_mfma<<<NWIN * NH / 4, 256, 0, stream>>>(regA, pos169, regB);

  // proj + residual(x fp32): regB -> d_out (fp32 x2)
  gemm_k<1><<<dim3(3, 392), 256, 0, stream>>>(regB, projT, proj_b, x, out,
                                              TT, 384, 384, 0);

  // LN2: d_out(fp32) -> regB(bf16)
  ln_kernel<<<TT / 4, 256, 0, stream>>>(out, n2g, n2b, regB);

  // MLP in 2 row-chunks of 25088 (hidden bf16 reuses regA)
  for (int ch = 0; ch < 2; ch++) {
    const u16* h2c = regB + (size_t)ch * 25088 * 384;
    gemm_k<2><<<dim3(12, 196), 256, 0, stream>>>(h2c, fc1T, fc1_b, nullptr, regA,
                                                 25088, 1536, 384, 0);
    gemm_k<1><<<dim3(3, 196), 256, 0, stream>>>(regA, fc2T, fc2_b, out, out,
                                                25088, 384, 1536, ch * 25088);
  }
}

// Round 4
// 664.244 us; speedup vs baseline: 1.7047x; 1.1524x over previous
//
#include <hip/hip_runtime.h>

typedef unsigned short u16;
typedef short s16x8 __attribute__((ext_vector_type(8)));
typedef short s16x4 __attribute__((ext_vector_type(4)));
typedef float f32x4 __attribute__((ext_vector_type(4)));
typedef float f32x2 __attribute__((ext_vector_type(2)));

#define B_ 64
#define Hh 28
#define Ww 28
#define Cc 384
#define Gg 7
#define Nn 49
#define NH 12
#define HD 32
#define TT 50176            // B*H*W tokens
#define NWIN 1024           // B * 16 windows
#define QKV_ELEMS 19267584u // 1024*12*49*32 per q/k/v
#define SCALE_Q 0.17677669529663687f

__device__ __forceinline__ float b2f(u16 u) {
  union { unsigned int i; float f; } v; v.i = ((unsigned int)u) << 16; return v.f;
}
__device__ __forceinline__ u16 f2b(float f) {
  union { float f; unsigned int i; } v; v.f = f;
  unsigned int r = v.i + 0x7fffu + ((v.i >> 16) & 1u);
  return (u16)(r >> 16);
}

__device__ __forceinline__ void gload_lds16(const u16* g, u16* l) {
  __builtin_amdgcn_global_load_lds(
      (const __attribute__((address_space(1))) unsigned int*)(const void*)g,
      (__attribute__((address_space(3))) unsigned int*)(void*)l, 16, 0, 0);
}

// ------------- transpose + fp32->bf16 cast: in[K][N] fp32 -> out[N][K] bf16 -------------
__global__ void transpose_f2b(const float* __restrict__ in, u16* __restrict__ out,
                              int K, int N) {
  int i = blockIdx.x * 256 + threadIdx.x;
  if (i < K * N) {
    int k = i / N, n = i % N;
    out[(size_t)n * K + k] = f2b(in[i]);
  }
}

// ---------------- dynamic position bias MLP (169 rows), fp32 in/out ----------------
__global__ __launch_bounds__(256)
void pos_mlp_kernel(const float* __restrict__ pp_w, const float* __restrict__ pp_b,
                    const float* __restrict__ l1g, const float* __restrict__ l1b,
                    const float* __restrict__ p1w, const float* __restrict__ p1b,
                    const float* __restrict__ l2g, const float* __restrict__ l2b,
                    const float* __restrict__ p2w, const float* __restrict__ p2b,
                    const float* __restrict__ l3g, const float* __restrict__ l3b,
                    const float* __restrict__ p3w, const float* __restrict__ p3b,
                    float* __restrict__ pos169) {
  __shared__ float w0[48], bb0[24], g1[24], e1[24], w1[576], bb1[24],
                   g2[24], e2[24], w2[576], bb2[24], g3[24], e3[24], w3[288], bb3[12];
  int tid = threadIdx.x;
  for (int i = tid; i < 48; i += 256) w0[i] = pp_w[i];
  for (int i = tid; i < 24; i += 256) {
    bb0[i] = pp_b[i]; g1[i] = l1g[i]; e1[i] = l1b[i]; bb1[i] = p1b[i];
    g2[i] = l2g[i]; e2[i] = l2b[i]; bb2[i] = p2b[i];
    g3[i] = l3g[i]; e3[i] = l3b[i];
  }
  for (int i = tid; i < 576; i += 256) { w1[i] = p1w[i]; w2[i] = p2w[i]; }
  for (int i = tid; i < 288; i += 256) w3[i] = p3w[i];
  for (int i = tid; i < 12; i += 256) bb3[i] = p3b[i];
  __syncthreads();
  if (tid < 169) {
    float bi = (float)(tid / 13) - 6.f, bj = (float)(tid % 13) - 6.f;
    float cur[24], t[24];
    #pragma unroll
    for (int c = 0; c < 24; c++) cur[c] = bi * w0[c] + bj * w0[24 + c] + bb0[c];

    auto lnrelu = [&](const float* gg, const float* ee) {
      float s = 0.f, sq = 0.f;
      #pragma unroll
      for (int c = 0; c < 24; c++) { s += cur[c]; sq += cur[c] * cur[c]; }
      float mean = s * (1.f / 24.f);
      float var = sq * (1.f / 24.f) - mean * mean;
      float rstd = rsqrtf(var + 1e-5f);
      #pragma unroll
      for (int c = 0; c < 24; c++)
        t[c] = fmaxf(0.f, (cur[c] - mean) * rstd * gg[c] + ee[c]);
    };

    lnrelu(g1, e1);
    #pragma unroll
    for (int o = 0; o < 24; o++) {
      float a = bb1[o];
      #pragma unroll
      for (int c = 0; c < 24; c++) a += t[c] * w1[c * 24 + o];
      cur[o] = a;
    }
    lnrelu(g2, e2);
    #pragma unroll
    for (int o = 0; o < 24; o++) {
      float a = bb2[o];
      #pragma unroll
      for (int c = 0; c < 24; c++) a += t[c] * w2[c * 24 + o];
      cur[o] = a;
    }
    lnrelu(g3, e3);
    #pragma unroll
    for (int h = 0; h < 12; h++) {
      float a = bb3[h];
      #pragma unroll
      for (int c = 0; c < 24; c++) a += t[c] * w3[c * 12 + h];
      pos169[tid * 12 + h] = a;
    }
  }
}

// ------------- LayerNorm over C=384: fp32 in -> bf16 out, one wave per row -------------
__global__ __launch_bounds__(256)
void ln_kernel(const float* __restrict__ x, const float* __restrict__ g,
               const float* __restrict__ be, u16* __restrict__ out) {
  int wid = threadIdx.x >> 6, lane = threadIdx.x & 63;
  size_t row = (size_t)blockIdx.x * 4 + wid;
  const float* xr = x + row * Cc;
  float v[6];
  float s = 0.f, sq = 0.f;
  #pragma unroll
  for (int p = 0; p < 3; p++) {
    f32x2 u = *(const f32x2*)&xr[p * 128 + lane * 2];
    v[2 * p] = u.x; v[2 * p + 1] = u.y;
    s += u.x + u.y; sq += u.x * u.x + u.y * u.y;
  }
  #pragma unroll
  for (int off = 32; off > 0; off >>= 1) { s += __shfl_xor(s, off); sq += __shfl_xor(sq, off); }
  float mean = s * (1.f / 384.f);
  float var = sq * (1.f / 384.f) - mean * mean;
  float rstd = rsqrtf(var + 1e-5f);
  u16* orow = out + row * Cc;
  #pragma unroll
  for (int p = 0; p < 3; p++) {
    int c = p * 128 + lane * 2;
    f32x2 ug = *(const f32x2*)&g[c];
    f32x2 ub = *(const f32x2*)&be[c];
    float o0 = (v[2 * p] - mean) * rstd * ug.x + ub.x;
    float o1 = (v[2 * p + 1] - mean) * rstd * ug.y + ub.y;
    unsigned int uo = (unsigned int)f2b(o0) | ((unsigned int)f2b(o1) << 16);
    *(unsigned int*)&orow[c] = uo;
  }
}

// ---------------- MFMA GEMM: C[M][N] = A[M][K] * Bt[N][K]^T, 128x128 tile ----------------
// 1D grid, XCD-chunked tile swizzle; global_load_lds staging with XOR-swizzled LDS.
// EPI 0: qkv scatter (+bias, q*SCALE) into [3][1024][12][49][32] bf16
// EPI 1: +bias +res(fp32), store fp32 (proj / fc2 residual)
// EPI 2: +bias, exact GELU, store bf16 [row*1536+col]
template <int EPI>
__global__ __launch_bounds__(256, 4)
void gemm_k(const u16* __restrict__ A, const u16* __restrict__ Bt,
            const float* __restrict__ bias, const void* resv, void* outv,
            int K, int gridX, int rowoff) {
  __shared__ u16 As[128 * 32];
  __shared__ u16 Bs[128 * 32];
  const int tid = threadIdx.x;
  const int wid = tid >> 6, lane = tid & 63;
  const int wr = (wid >> 1) * 64, wc = (wid & 1) * 64;
  const int lm = lane & 15, lq = lane >> 4;

  // XCD-chunk swizzle: xcd = blockIdx%8 owns a contiguous run of tiles
  {
  }
  const int total = gridDim.x;
  const int xcd = blockIdx.x & 7, pos = blockIdx.x >> 3;
  const int cbase = total >> 3, crem = total & 7;
  const int tile = (xcd < crem) ? (xcd * (cbase + 1) + pos)
                                : (crem * (cbase + 1) + (xcd - crem) * cbase + pos);
  const int mTile = tile / gridX;
  const int nTile = tile - mTile * gridX;
  const int mBase = mTile * 128, nBase = nTile * 128;

  // staging map: lane element row r = s*64 + (tid>>2), stored slot (tid&3),
  // holds global col-group g = (tid&3) ^ ((tid>>3)&3)   (16B per slot)
  const int srow = tid >> 2;
  const int sg = (tid & 3) ^ ((tid >> 3) & 3);
  const size_t aRow0 = (size_t)(mBase + srow) * K + sg * 8;
  const size_t aRow1 = (size_t)(mBase + 64 + srow) * K + sg * 8;
  const size_t bRow0 = (size_t)(nBase + srow) * K + sg * 8;
  const size_t bRow1 = (size_t)(nBase + 64 + srow) * K + sg * 8;
  u16* aDst0 = As + tid * 8;          // slot (s*256+tid) * 8 u16
  u16* aDst1 = As + 2048 + tid * 8;
  u16* bDst0 = Bs + tid * 8;
  u16* bDst1 = Bs + 2048 + tid * 8;

  // frag read slots
  int aslot[4], bslot[4];
  #pragma unroll
  for (int i = 0; i < 4; i++) {
    int ar = wr + i * 16 + lm;
    aslot[i] = ar * 32 + (lq ^ ((ar >> 1) & 3)) * 8;
    int br = wc + i * 16 + lm;
    bslot[i] = br * 32 + (lq ^ ((br >> 1) & 3)) * 8;
  }

  f32x4 acc[4][4] = {};
  for (int k0 = 0; k0 < K; k0 += 32) {
    gload_lds16(A + aRow0 + k0, aDst0);
    gload_lds16(A + aRow1 + k0, aDst1);
    gload_lds16(Bt + bRow0 + k0, bDst0);
    gload_lds16(Bt + bRow1 + k0, bDst1);
    __syncthreads();
    s16x8 af[4], bfr[4];
    #pragma unroll
    for (int i = 0; i < 4; i++) af[i] = *(const s16x8*)&As[aslot[i]];
    #pragma unroll
    for (int j = 0; j < 4; j++) bfr[j] = *(const s16x8*)&Bs[bslot[j]];
    #pragma unroll
    for (int i = 0; i < 4; i++)
      #pragma unroll
      for (int j = 0; j < 4; j++)
        acc[i][j] = __builtin_amdgcn_mfma_f32_16x16x32_bf16(af[i], bfr[j], acc[i][j], 0, 0, 0);
    __syncthreads();
  }

  int colA[4]; float bvv[4];
  #pragma unroll
  for (int j = 0; j < 4; j++) {
    colA[j] = nBase + wc + j * 16 + lm;
    bvv[j] = bias[colA[j]];
  }

  if constexpr (EPI == 0) {
    u16* out = (u16*)outv;
    size_t offj[4]; float scl[4];
    #pragma unroll
    for (int j = 0; j < 4; j++) {
      int col = colA[j];
      int qi = col / 384, c2 = col % 384;
      int head = c2 >> 5, d = c2 & 31;
      offj[j] = (size_t)qi * QKV_ELEMS + (size_t)head * 1568 + d;
      scl[j] = (qi == 0) ? SCALE_Q : 1.0f;
    }
    #pragma unroll
    for (int i = 0; i < 4; i++) {
      #pragma unroll
      for (int rg = 0; rg < 4; rg++) {
        int t = mBase + wr + i * 16 + lq * 4 + rg;
        int b_ = t / 784, rr = t % 784;
        int hh = rr / 28, ww = rr % 28;
        int widx = b_ * 16 + (hh / 7) * 4 + (ww / 7);
        int n = (hh % 7) * 7 + (ww % 7);
        size_t offr = (size_t)widx * 18816 + n * 32;
        #pragma unroll
        for (int j = 0; j < 4; j++)
          out[offj[j] + offr] = f2b((acc[i][j][rg] + bvv[j]) * scl[j]);
      }
    }
  } else if constexpr (EPI == 1) {
    float* out = (float*)outv;
    const float* res = (const float*)resv;
    #pragma unroll
    for (int i = 0; i < 4; i++) {
      #pragma unroll
      for (int rg = 0; rg < 4; rg++) {
        size_t rb = (size_t)(rowoff + mBase + wr + i * 16 + lq * 4 + rg) * 384;
        #pragma unroll
        for (int j = 0; j < 4; j++) {
          size_t o = rb + colA[j];
          out[o] = acc[i][j][rg] + bvv[j] + res[o];
        }
      }
    }
  } else {  // EPI == 2: GELU -> bf16
    u16* out = (u16*)outv;
    #pragma unroll
    for (int i = 0; i < 4; i++) {
      #pragma unroll
      for (int rg = 0; rg < 4; rg++) {
        size_t rb = (size_t)(mBase + wr + i * 16 + lq * 4 + rg) * 1536;
        #pragma unroll
        for (int j = 0; j < 4; j++) {
          float v = acc[i][j][rg] + bvv[j];
          float gl = 0.5f * v * (1.0f + erff(v * 0.70710678118654752f));
          out[rb + colA[j]] = f2b(gl);
        }
      }
    }
  }
}

// ---------------- MFMA attention: one wave per (window, head), 4 waves/block ----------------
__global__ __launch_bounds__(256, 3)
void attn_mfma(const u16* __restrict__ qkv, const float* __restrict__ pos169,
               u16* __restrict__ attn_out) {
  __shared__ u16 P_l[4][64 * 68];     // per-wave P matrix, stride 68 (writes 2-way free)
  __shared__ float bias_l[4][170];
  const int wid = threadIdx.x >> 6, lane = threadIdx.x & 63;
  const int lm = lane & 15, lq = lane >> 4;
  const int pair = blockIdx.x * 4 + wid;
  const int widx = pair / 12, head = pair % 12;
  const u16* qp = qkv + (size_t)widx * 18816 + head * 1568;
  const u16* kp = qp + QKV_ELEMS;
  const u16* vp = kp + QKV_ELEMS;

  for (int i = lane; i < 169; i += 64) bias_l[wid][i] = pos169[i * 12 + head];

  // Q (A-op) and K (B-op) fragments straight from global: lane holds 8 contiguous d.
  s16x8 aq[4], bk[4];
  #pragma unroll
  for (int i = 0; i < 4; i++) aq[i] = *(const s16x8*)&qp[(i * 16 + lm) * 32 + lq * 8];
  #pragma unroll
  for (int j = 0; j < 4; j++) bk[j] = *(const s16x8*)&kp[(j * 16 + lm) * 32 + lq * 8];

  // scores: acc[i][j], row n = i*16+lq*4+rg, col m = j*16+lm   (K=32 in one step)
  f32x4 acc[4][4] = {};
  #pragma unroll
  for (int i = 0; i < 4; i++)
    #pragma unroll
    for (int j = 0; j < 4; j++)
      acc[i][j] = __builtin_amdgcn_mfma_f32_16x16x32_bf16(aq[i], bk[j], acc[i][j], 0, 0, 0);

  // per-column (m) constants
  int mj[4], mhj[4], mwj[4];
  #pragma unroll
  for (int j = 0; j < 4; j++) {
    mj[j] = j * 16 + lm; mhj[j] = mj[j] / 7; mwj[j] = mj[j] - mhj[j] * 7;
  }

  // bias + mask + softmax (row n spans 4 j-regs x 16 lanes of same lq group)
  #pragma unroll
  for (int i = 0; i < 4; i++) {
    #pragma unroll
    for (int rg = 0; rg < 4; rg++) {
      int n = i * 16 + lq * 4 + rg;
      int nh = n / 7, nw = n - nh * 7;
      float s[4];
      #pragma unroll
      for (int j = 0; j < 4; j++) {
        int idx = (nh - mhj[j] + 6) * 13 + (nw - mwj[j] + 6);
        idx = min(max(idx, 0), 168);
        s[j] = acc[i][j][rg] + bias_l[wid][idx];
        if (mj[j] >= 49) s[j] = -3.0e30f;
      }
      float mx = fmaxf(fmaxf(s[0], s[1]), fmaxf(s[2], s[3]));
      #pragma unroll
      for (int off = 1; off < 16; off <<= 1) mx = fmaxf(mx, __shfl_xor(mx, off));
      float e[4];
      float sm = 0.f;
      #pragma unroll
      for (int j = 0; j < 4; j++) { e[j] = __expf(s[j] - mx); sm += e[j]; }
      #pragma unroll
      for (int off = 1; off < 16; off <<= 1) sm += __shfl_xor(sm, off);
      float r = 1.0f / sm;
      #pragma unroll
      for (int j = 0; j < 4; j++)
        P_l[wid][n * 68 + mj[j]] = f2b(e[j] * r);
    }
  }

  // PV: A = P from LDS (2x b64 per frag, 8B-aligned), B = V^T via strided global loads
  s16x8 ap[4][2];
  #pragma unroll
  for (int i = 0; i < 4; i++)
    #pragma unroll
    for (int ks = 0; ks < 2; ks++) {
      const u16* p = &P_l[wid][(i * 16 + lm) * 68 + ks * 32 + lq * 8];
      s16x4 lo = *(const s16x4*)p;
      s16x4 hi = *(const s16x4*)(p + 4);
      ap[i][ks] = __builtin_shufflevector(lo, hi, 0, 1, 2, 3, 4, 5, 6, 7);
    }
  s16x8 bv[2][2];
  #pragma unroll
  for (int jt = 0; jt < 2; jt++)
    #pragma unroll
    for (int ks = 0; ks < 2; ks++) {
      s16x8 v;
      #pragma unroll
      for (int jj = 0; jj < 8; jj++)
        v[jj] = (short)vp[(ks * 32 + lq * 8 + jj) * 32 + jt * 16 + lm];
      bv[jt][ks] = v;
    }

  f32x4 o[4][2] = {};
  #pragma unroll
  for (int i = 0; i < 4; i++)
    #pragma unroll
    for (int jt = 0; jt < 2; jt++)
      #pragma unroll
      for (int ks = 0; ks < 2; ks++)
        o[i][jt] = __builtin_amdgcn_mfma_f32_16x16x32_bf16(ap[i][ks], bv[jt][ks], o[i][jt], 0, 0, 0);

  // epilogue: row n = i*16+lq*4+rg, col d = jt*16+lm -> attn_out[t*384 + head*32 + d]
  const int b_ = widx >> 4, wq = widx & 15;
  const int hbase = (wq >> 2) * 7, wbase = (wq & 3) * 7;
  #pragma unroll
  for (int i = 0; i < 4; i++) {
    #pragma unroll
    for (int rg = 0; rg < 4; rg++) {
      int n = i * 16 + lq * 4 + rg;
      if (n < 49) {
        int nh = n / 7, nw = n - nh * 7;
        int t = b_ * 784 + (hbase + nh) * 28 + (wbase + nw);
        size_t ob = (size_t)t * 384 + head * 32 + lm;
        attn_out[ob] = f2b(o[i][0][rg]);
        attn_out[ob + 16] = f2b(o[i][1][rg]);
      }
    }
  }
}

extern "C" void kernel_launch(void* const* d_in, const int* in_sizes, int n_in,
                              void* d_out, int out_size, void* d_ws, size_t ws_size,
                              hipStream_t stream) {
  const float* x      = (const float*)d_in[0];
  const float* n1g    = (const float*)d_in[1];
  const float* n1b    = (const float*)d_in[2];
  const float* qkv_w  = (const float*)d_in[3];
  const float* qkv_b  = (const float*)d_in[4];
  const float* proj_w = (const float*)d_in[5];
  const float* proj_b = (const float*)d_in[6];
  const float* n2g    = (const float*)d_in[7];
  const float* n2b    = (const float*)d_in[8];
  const float* fc1_w  = (const float*)d_in[9];
  const float* fc1_b  = (const float*)d_in[10];
  const float* fc2_w  = (const float*)d_in[11];
  const float* fc2_b  = (const float*)d_in[12];

  // ws layout (bytes)
  const size_t SZ_A = 115605504;   // qkv (3*1024*12*49*32 bf16) / MLP hidden chunks
  const size_t SZ_B = 38535168;    // h (LN out) / attn_out / h2 (bf16)
  char* wsb = (char*)d_ws;
  u16* regA     = (u16*)wsb;
  u16* regB     = (u16*)(wsb + SZ_A);
  float* pos169 = (float*)(wsb + SZ_A + SZ_B);
  u16* qkvT     = (u16*)(wsb + SZ_A + SZ_B + 8192);
  u16* projT    = qkvT + 442368;
  u16* fc1T     = projT + 147456;
  u16* fc2T     = fc1T + 589824;

  float* out = (float*)d_out;

  // weight transposes [K][N] fp32 -> [N][K] bf16
  transpose_f2b<<<1728, 256, 0, stream>>>(qkv_w, qkvT, 384, 1152);
  transpose_f2b<<<576, 256, 0, stream>>>(proj_w, projT, 384, 384);
  transpose_f2b<<<2304, 256, 0, stream>>>(fc1_w, fc1T, 384, 1536);
  transpose_f2b<<<2304, 256, 0, stream>>>(fc2_w, fc2T, 1536, 384);

  // dynamic position bias table [169][12] fp32
  pos_mlp_kernel<<<1, 256, 0, stream>>>(
      (const float*)d_in[13], (const float*)d_in[14], (const float*)d_in[15], (const float*)d_in[16],
      (const float*)d_in[17], (const float*)d_in[18], (const float*)d_in[19], (const float*)d_in[20],
      (const float*)d_in[21], (const float*)d_in[22], (const float*)d_in[23], (const float*)d_in[24],
      (const float*)d_in[25], (const float*)d_in[26], pos169);

  // LN1: x(fp32) -> regB(bf16)
  ln_kernel<<<TT / 4, 256, 0, stream>>>(x, n1g, n1b, regB);

  // QKV GEMM with window scatter: regB -> regA (bf16).  392x9 tiles
  gemm_k<0><<<392 * 9, 256, 0, stream>>>(regB, qkvT, qkv_b, nullptr, regA,
                                         384, 9, 0);

  // attention (MFMA): regA -> regB (attn_out bf16, token order)
  attn_mfma<<<NWIN * NH / 4, 256, 0, stream>>>(regA, pos169, regB);

  // proj + residual(x fp32): regB -> d_out (fp32 x2).  392x3 tiles
  gemm_k<1><<<392 * 3, 256, 0, stream>>>(regB, projT, proj_b, x, out,
                                         384, 3, 0);

  // LN2: d_out(fp32) -> regB(bf16)
  ln_kernel<<<TT / 4, 256, 0, stream>>>(out, n2g, n2b, regB);

  // MLP in 2 row-chunks of 25088 (hidden bf16 reuses regA)
  for (int ch = 0; ch < 2; ch++) {
    const u16* h2c = regB + (size_t)ch * 25088 * 384;
    gemm_k<2><<<196 * 12, 256, 0, stream>>>(h2c, fc1T, fc1_b, nullptr, regA,
                                            384, 12, 0);
    gemm_k<1><<<196 * 3, 256, 0, stream>>>(regA, fc2T, fc2_b, out, out,
                                           1536, 3, ch * 25088);
  }
}

// Round 5
// 656.575 us; speedup vs baseline: 1.7246x; 1.0117x over previous
//
#include <hip/hip_runtime.h>

typedef unsigned short u16;
typedef short s16x8 __attribute__((ext_vector_type(8)));
typedef short s16x4 __attribute__((ext_vector_type(4)));
typedef float f32x4 __attribute__((ext_vector_type(4)));
typedef float f32x2 __attribute__((ext_vector_type(2)));

#define B_ 64
#define Hh 28
#define Ww 28
#define Cc 384
#define Gg 7
#define Nn 49
#define NH 12
#define HD 32
#define TT 50176            // B*H*W tokens
#define NWIN 1024           // B * 16 windows
#define QKV_ELEMS 19267584u // 1024*12*49*32 per q/k/v
#define SCALE_Q 0.17677669529663687f

__device__ __forceinline__ float b2f(u16 u) {
  union { unsigned int i; float f; } v; v.i = ((unsigned int)u) << 16; return v.f;
}
__device__ __forceinline__ u16 f2b(float f) {
  union { float f; unsigned int i; } v; v.f = f;
  unsigned int r = v.i + 0x7fffu + ((v.i >> 16) & 1u);
  return (u16)(r >> 16);
}

__device__ __forceinline__ void gload_lds16(const u16* g, u16* l) {
  __builtin_amdgcn_global_load_lds(
      (const __attribute__((address_space(1))) unsigned int*)(const void*)g,
      (__attribute__((address_space(3))) unsigned int*)(void*)l, 16, 0, 0);
}

// ------- merged transpose + fp32->bf16 cast: 4 weights, in[K][N] fp32 -> out[N][K] bf16 ----
__global__ void transpose_all(const float* __restrict__ w0, u16* __restrict__ o0,
                              const float* __restrict__ w1, u16* __restrict__ o1,
                              const float* __restrict__ w2, u16* __restrict__ o2,
                              const float* __restrict__ w3, u16* __restrict__ o3) {
  int b = blockIdx.x;
  const float* in; u16* out; int K, N, base;
  if (b < 1728)      { in = w0; out = o0; K = 384;  N = 1152; base = b; }
  else if (b < 2304) { in = w1; out = o1; K = 384;  N = 384;  base = b - 1728; }
  else if (b < 4608) { in = w2; out = o2; K = 384;  N = 1536; base = b - 2304; }
  else               { in = w3; out = o3; K = 1536; N = 384;  base = b - 4608; }
  int i = base * 256 + threadIdx.x;
  if (i < K * N) {
    int k = i / N, n = i % N;
    out[(size_t)n * K + k] = f2b(in[i]);
  }
}

// ---------------- dynamic position bias MLP (169 rows), fp32 in/out ----------------
__global__ __launch_bounds__(256)
void pos_mlp_kernel(const float* __restrict__ pp_w, const float* __restrict__ pp_b,
                    const float* __restrict__ l1g, const float* __restrict__ l1b,
                    const float* __restrict__ p1w, const float* __restrict__ p1b,
                    const float* __restrict__ l2g, const float* __restrict__ l2b,
                    const float* __restrict__ p2w, const float* __restrict__ p2b,
                    const float* __restrict__ l3g, const float* __restrict__ l3b,
                    const float* __restrict__ p3w, const float* __restrict__ p3b,
                    float* __restrict__ pos169) {
  __shared__ float w0[48], bb0[24], g1[24], e1[24], w1[576], bb1[24],
                   g2[24], e2[24], w2[576], bb2[24], g3[24], e3[24], w3[288], bb3[12];
  int tid = threadIdx.x;
  for (int i = tid; i < 48; i += 256) w0[i] = pp_w[i];
  for (int i = tid; i < 24; i += 256) {
    bb0[i] = pp_b[i]; g1[i] = l1g[i]; e1[i] = l1b[i]; bb1[i] = p1b[i];
    g2[i] = l2g[i]; e2[i] = l2b[i]; bb2[i] = p2b[i];
    g3[i] = l3g[i]; e3[i] = l3b[i];
  }
  for (int i = tid; i < 576; i += 256) { w1[i] = p1w[i]; w2[i] = p2w[i]; }
  for (int i = tid; i < 288; i += 256) w3[i] = p3w[i];
  for (int i = tid; i < 12; i += 256) bb3[i] = p3b[i];
  __syncthreads();
  if (tid < 169) {
    float bi = (float)(tid / 13) - 6.f, bj = (float)(tid % 13) - 6.f;
    float cur[24], t[24];
    #pragma unroll
    for (int c = 0; c < 24; c++) cur[c] = bi * w0[c] + bj * w0[24 + c] + bb0[c];

    auto lnrelu = [&](const float* gg, const float* ee) {
      float s = 0.f, sq = 0.f;
      #pragma unroll
      for (int c = 0; c < 24; c++) { s += cur[c]; sq += cur[c] * cur[c]; }
      float mean = s * (1.f / 24.f);
      float var = sq * (1.f / 24.f) - mean * mean;
      float rstd = rsqrtf(var + 1e-5f);
      #pragma unroll
      for (int c = 0; c < 24; c++)
        t[c] = fmaxf(0.f, (cur[c] - mean) * rstd * gg[c] + ee[c]);
    };

    lnrelu(g1, e1);
    #pragma unroll
    for (int o = 0; o < 24; o++) {
      float a = bb1[o];
      #pragma unroll
      for (int c = 0; c < 24; c++) a += t[c] * w1[c * 24 + o];
      cur[o] = a;
    }
    lnrelu(g2, e2);
    #pragma unroll
    for (int o = 0; o < 24; o++) {
      float a = bb2[o];
      #pragma unroll
      for (int c = 0; c < 24; c++) a += t[c] * w2[c * 24 + o];
      cur[o] = a;
    }
    lnrelu(g3, e3);
    #pragma unroll
    for (int h = 0; h < 12; h++) {
      float a = bb3[h];
      #pragma unroll
      for (int c = 0; c < 24; c++) a += t[c] * w3[c * 12 + h];
      pos169[tid * 12 + h] = a;
    }
  }
}

// ------------- LayerNorm over C=384: fp32 in -> bf16 out, one wave per row -------------
__global__ __launch_bounds__(256)
void ln_kernel(const float* __restrict__ x, const float* __restrict__ g,
               const float* __restrict__ be, u16* __restrict__ out) {
  int wid = threadIdx.x >> 6, lane = threadIdx.x & 63;
  size_t row = (size_t)blockIdx.x * 4 + wid;
  const float* xr = x + row * Cc;
  float v[6];
  float s = 0.f, sq = 0.f;
  #pragma unroll
  for (int p = 0; p < 3; p++) {
    f32x2 u = *(const f32x2*)&xr[p * 128 + lane * 2];
    v[2 * p] = u.x; v[2 * p + 1] = u.y;
    s += u.x + u.y; sq += u.x * u.x + u.y * u.y;
  }
  #pragma unroll
  for (int off = 32; off > 0; off >>= 1) { s += __shfl_xor(s, off); sq += __shfl_xor(sq, off); }
  float mean = s * (1.f / 384.f);
  float var = sq * (1.f / 384.f) - mean * mean;
  float rstd = rsqrtf(var + 1e-5f);
  u16* orow = out + row * Cc;
  #pragma unroll
  for (int p = 0; p < 3; p++) {
    int c = p * 128 + lane * 2;
    f32x2 ug = *(const f32x2*)&g[c];
    f32x2 ub = *(const f32x2*)&be[c];
    float o0 = (v[2 * p] - mean) * rstd * ug.x + ub.x;
    float o1 = (v[2 * p + 1] - mean) * rstd * ug.y + ub.y;
    unsigned int uo = (unsigned int)f2b(o0) | ((unsigned int)f2b(o1) << 16);
    *(unsigned int*)&orow[c] = uo;
  }
}

// ---------------- MFMA GEMM: C[M][N] = A[M][K] * Bt[N][K]^T, 128x128 tile ----------------
// Double-buffered LDS with prefetch-before-compute: one barrier per K-iter, next tile's
// global_load_lds DMA in flight during current tile's MFMA phase.
// 1D grid, XCD-chunked tile swizzle; XOR-swizzled LDS (conflict-free).
// EPI 0: qkv scatter (+bias, q*SCALE) into [3][1024][12][49][32] bf16
// EPI 1: +bias +res(fp32), store fp32 (proj / fc2 residual)
// EPI 2: +bias, exact GELU, store bf16 [row*1536+col]
template <int EPI>
__global__ __launch_bounds__(256, 4)
void gemm_k(const u16* __restrict__ A, const u16* __restrict__ Bt,
            const float* __restrict__ bias, const void* resv, void* outv,
            int K, int gridX, int rowoff) {
  __shared__ u16 As[2][4096];
  __shared__ u16 Bs[2][4096];
  const int tid = threadIdx.x;
  const int wid = tid >> 6, lane = tid & 63;
  const int wr = (wid >> 1) * 64, wc = (wid & 1) * 64;
  const int lm = lane & 15, lq = lane >> 4;

  // XCD-chunk swizzle: xcd = blockIdx%8 owns a contiguous run of tiles
  const int total = gridDim.x;
  const int xcd = blockIdx.x & 7, pos = blockIdx.x >> 3;
  const int cbase = total >> 3, crem = total & 7;
  const int tile = (xcd < crem) ? (xcd * (cbase + 1) + pos)
                                : (crem * (cbase + 1) + (xcd - crem) * cbase + pos);
  const int mTile = tile / gridX;
  const int nTile = tile - mTile * gridX;
  const int mBase = mTile * 128, nBase = nTile * 128;

  // staging map: element row r = s*64 + (tid>>2), slot (tid&3),
  // holds global col-group g = (tid&3) ^ ((tid>>3)&3)   (16B per slot)
  const int srow = tid >> 2;
  const int sg = (tid & 3) ^ ((tid >> 3) & 3);
  const size_t aRow0 = (size_t)(mBase + srow) * K + sg * 8;
  const size_t aRow1 = (size_t)(mBase + 64 + srow) * K + sg * 8;
  const size_t bRow0 = (size_t)(nBase + srow) * K + sg * 8;
  const size_t bRow1 = (size_t)(nBase + 64 + srow) * K + sg * 8;

  // frag read slots
  int aslot[4], bslot[4];
  #pragma unroll
  for (int i = 0; i < 4; i++) {
    int ar = wr + i * 16 + lm;
    aslot[i] = ar * 32 + (lq ^ ((ar >> 1) & 3)) * 8;
    int br = wc + i * 16 + lm;
    bslot[i] = br * 32 + (lq ^ ((br >> 1) & 3)) * 8;
  }

  auto stage = [&](int k0, int b) {
    gload_lds16(A + aRow0 + k0, As[b] + tid * 8);
    gload_lds16(A + aRow1 + k0, As[b] + 2048 + tid * 8);
    gload_lds16(Bt + bRow0 + k0, Bs[b] + tid * 8);
    gload_lds16(Bt + bRow1 + k0, Bs[b] + 2048 + tid * 8);
  };

  const int kIters = K >> 5;
  f32x4 acc[4][4] = {};
  stage(0, 0);
  __syncthreads();
  for (int k = 0; k < kIters; k++) {
    const int cb = k & 1;
    if (k + 1 < kIters) stage((k + 1) << 5, cb ^ 1);
    s16x8 af[4], bfr[4];
    #pragma unroll
    for (int i = 0; i < 4; i++) af[i] = *(const s16x8*)&As[cb][aslot[i]];
    #pragma unroll
    for (int j = 0; j < 4; j++) bfr[j] = *(const s16x8*)&Bs[cb][bslot[j]];
    #pragma unroll
    for (int i = 0; i < 4; i++)
      #pragma unroll
      for (int j = 0; j < 4; j++)
        acc[i][j] = __builtin_amdgcn_mfma_f32_16x16x32_bf16(af[i], bfr[j], acc[i][j], 0, 0, 0);
    __syncthreads();
  }

  int colA[4]; float bvv[4];
  #pragma unroll
  for (int j = 0; j < 4; j++) {
    colA[j] = nBase + wc + j * 16 + lm;
    bvv[j] = bias[colA[j]];
  }

  if constexpr (EPI == 0) {
    u16* out = (u16*)outv;
    size_t offj[4]; float scl[4];
    #pragma unroll
    for (int j = 0; j < 4; j++) {
      int col = colA[j];
      int qi = col / 384, c2 = col % 384;
      int head = c2 >> 5, d = c2 & 31;
      offj[j] = (size_t)qi * QKV_ELEMS + (size_t)head * 1568 + d;
      scl[j] = (qi == 0) ? SCALE_Q : 1.0f;
    }
    #pragma unroll
    for (int i = 0; i < 4; i++) {
      #pragma unroll
      for (int rg = 0; rg < 4; rg++) {
        int t = mBase + wr + i * 16 + lq * 4 + rg;
        int b_ = t / 784, rr = t % 784;
        int hh = rr / 28, ww = rr % 28;
        int widx = b_ * 16 + (hh / 7) * 4 + (ww / 7);
        int n = (hh % 7) * 7 + (ww % 7);
        size_t offr = (size_t)widx * 18816 + n * 32;
        #pragma unroll
        for (int j = 0; j < 4; j++)
          out[offj[j] + offr] = f2b((acc[i][j][rg] + bvv[j]) * scl[j]);
      }
    }
  } else if constexpr (EPI == 1) {
    float* out = (float*)outv;
    const float* res = (const float*)resv;
    #pragma unroll
    for (int i = 0; i < 4; i++) {
      #pragma unroll
      for (int rg = 0; rg < 4; rg++) {
        size_t rb = (size_t)(rowoff + mBase + wr + i * 16 + lq * 4 + rg) * 384;
        #pragma unroll
        for (int j = 0; j < 4; j++) {
          size_t o = rb + colA[j];
          out[o] = acc[i][j][rg] + bvv[j] + res[o];
        }
      }
    }
  } else {  // EPI == 2: GELU -> bf16
    u16* out = (u16*)outv;
    #pragma unroll
    for (int i = 0; i < 4; i++) {
      #pragma unroll
      for (int rg = 0; rg < 4; rg++) {
        size_t rb = (size_t)(mBase + wr + i * 16 + lq * 4 + rg) * 1536;
        #pragma unroll
        for (int j = 0; j < 4; j++) {
          float v = acc[i][j][rg] + bvv[j];
          float gl = 0.5f * v * (1.0f + erff(v * 0.70710678118654752f));
          out[rb + colA[j]] = f2b(gl);
        }
      }
    }
  }
}

// ---------------- MFMA attention: one wave per (window, head), 4 waves/block ----------------
__global__ __launch_bounds__(256, 3)
void attn_mfma(const u16* __restrict__ qkv, const float* __restrict__ pos169,
               u16* __restrict__ attn_out) {
  __shared__ u16 P_l[4][64 * 68];     // per-wave P matrix, stride 68 (writes 2-way free)
  __shared__ float bias_l[4][170];
  const int wid = threadIdx.x >> 6, lane = threadIdx.x & 63;
  const int lm = lane & 15, lq = lane >> 4;
  const int pair = blockIdx.x * 4 + wid;
  const int widx = pair / 12, head = pair % 12;
  const u16* qp = qkv + (size_t)widx * 18816 + head * 1568;
  const u16* kp = qp + QKV_ELEMS;
  const u16* vp = kp + QKV_ELEMS;

  for (int i = lane; i < 169; i += 64) bias_l[wid][i] = pos169[i * 12 + head];

  // Q (A-op) and K (B-op) fragments straight from global: lane holds 8 contiguous d.
  s16x8 aq[4], bk[4];
  #pragma unroll
  for (int i = 0; i < 4; i++) aq[i] = *(const s16x8*)&qp[(i * 16 + lm) * 32 + lq * 8];
  #pragma unroll
  for (int j = 0; j < 4; j++) bk[j] = *(const s16x8*)&kp[(j * 16 + lm) * 32 + lq * 8];

  // scores: acc[i][j], row n = i*16+lq*4+rg, col m = j*16+lm   (K=32 in one step)
  f32x4 acc[4][4] = {};
  #pragma unroll
  for (int i = 0; i < 4; i++)
    #pragma unroll
    for (int j = 0; j < 4; j++)
      acc[i][j] = __builtin_amdgcn_mfma_f32_16x16x32_bf16(aq[i], bk[j], acc[i][j], 0, 0, 0);

  // per-column (m) constants
  int mj[4], mhj[4], mwj[4];
  #pragma unroll
  for (int j = 0; j < 4; j++) {
    mj[j] = j * 16 + lm; mhj[j] = mj[j] / 7; mwj[j] = mj[j] - mhj[j] * 7;
  }

  // bias + mask + softmax (row n spans 4 j-regs x 16 lanes of same lq group)
  #pragma unroll
  for (int i = 0; i < 4; i++) {
    #pragma unroll
    for (int rg = 0; rg < 4; rg++) {
      int n = i * 16 + lq * 4 + rg;
      int nh = n / 7, nw = n - nh * 7;
      float s[4];
      #pragma unroll
      for (int j = 0; j < 4; j++) {
        int idx = (nh - mhj[j] + 6) * 13 + (nw - mwj[j] + 6);
        idx = min(max(idx, 0), 168);
        s[j] = acc[i][j][rg] + bias_l[wid][idx];
        if (mj[j] >= 49) s[j] = -3.0e30f;
      }
      float mx = fmaxf(fmaxf(s[0], s[1]), fmaxf(s[2], s[3]));
      #pragma unroll
      for (int off = 1; off < 16; off <<= 1) mx = fmaxf(mx, __shfl_xor(mx, off));
      float e[4];
      float sm = 0.f;
      #pragma unroll
      for (int j = 0; j < 4; j++) { e[j] = __expf(s[j] - mx); sm += e[j]; }
      #pragma unroll
      for (int off = 1; off < 16; off <<= 1) sm += __shfl_xor(sm, off);
      float r = 1.0f / sm;
      #pragma unroll
      for (int j = 0; j < 4; j++)
        P_l[wid][n * 68 + mj[j]] = f2b(e[j] * r);
    }
  }

  // PV: A = P from LDS (2x b64 per frag, 8B-aligned), B = V^T via strided global loads
  s16x8 ap[4][2];
  #pragma unroll
  for (int i = 0; i < 4; i++)
    #pragma unroll
    for (int ks = 0; ks < 2; ks++) {
      const u16* p = &P_l[wid][(i * 16 + lm) * 68 + ks * 32 + lq * 8];
      s16x4 lo = *(const s16x4*)p;
      s16x4 hi = *(const s16x4*)(p + 4);
      ap[i][ks] = __builtin_shufflevector(lo, hi, 0, 1, 2, 3, 4, 5, 6, 7);
    }
  s16x8 bv[2][2];
  #pragma unroll
  for (int jt = 0; jt < 2; jt++)
    #pragma unroll
    for (int ks = 0; ks < 2; ks++) {
      s16x8 v;
      #pragma unroll
      for (int jj = 0; jj < 8; jj++)
        v[jj] = (short)vp[(ks * 32 + lq * 8 + jj) * 32 + jt * 16 + lm];
      bv[jt][ks] = v;
    }

  f32x4 o[4][2] = {};
  #pragma unroll
  for (int i = 0; i < 4; i++)
    #pragma unroll
    for (int jt = 0; jt < 2; jt++)
      #pragma unroll
      for (int ks = 0; ks < 2; ks++)
        o[i][jt] = __builtin_amdgcn_mfma_f32_16x16x32_bf16(ap[i][ks], bv[jt][ks], o[i][jt], 0, 0, 0);

  // epilogue: row n = i*16+lq*4+rg, col d = jt*16+lm -> attn_out[t*384 + head*32 + d]
  const int b_ = widx >> 4, wq = widx & 15;
  const int hbase = (wq >> 2) * 7, wbase = (wq & 3) * 7;
  #pragma unroll
  for (int i = 0; i < 4; i++) {
    #pragma unroll
    for (int rg = 0; rg < 4; rg++) {
      int n = i * 16 + lq * 4 + rg;
      if (n < 49) {
        int nh = n / 7, nw = n - nh * 7;
        int t = b_ * 784 + (hbase + nh) * 28 + (wbase + nw);
        size_t ob = (size_t)t * 384 + head * 32 + lm;
        attn_out[ob] = f2b(o[i][0][rg]);
        attn_out[ob + 16] = f2b(o[i][1][rg]);
      }
    }
  }
}

extern "C" void kernel_launch(void* const* d_in, const int* in_sizes, int n_in,
                              void* d_out, int out_size, void* d_ws, size_t ws_size,
                              hipStream_t stream) {
  const float* x      = (const float*)d_in[0];
  const float* n1g    = (const float*)d_in[1];
  const float* n1b    = (const float*)d_in[2];
  const float* qkv_w  = (const float*)d_in[3];
  const float* qkv_b  = (const float*)d_in[4];
  const float* proj_w = (const float*)d_in[5];
  const float* proj_b = (const float*)d_in[6];
  const float* n2g    = (const float*)d_in[7];
  const float* n2b    = (const float*)d_in[8];
  const float* fc1_w  = (const float*)d_in[9];
  const float* fc1_b  = (const float*)d_in[10];
  const float* fc2_w  = (const float*)d_in[11];
  const float* fc2_b  = (const float*)d_in[12];

  // ws layout (bytes)
  const size_t SZ_A = 115605504;   // qkv (3*1024*12*49*32 bf16) / MLP hidden chunks
  const size_t SZ_B = 38535168;    // h (LN out) / attn_out / h2 (bf16)
  char* wsb = (char*)d_ws;
  u16* regA     = (u16*)wsb;
  u16* regB     = (u16*)(wsb + SZ_A);
  float* pos169 = (float*)(wsb + SZ_A + SZ_B);
  u16* qkvT     = (u16*)(wsb + SZ_A + SZ_B + 8192);
  u16* projT    = qkvT + 442368;
  u16* fc1T     = projT + 147456;
  u16* fc2T     = fc1T + 589824;

  float* out = (float*)d_out;

  // weight transposes [K][N] fp32 -> [N][K] bf16 (single merged launch)
  transpose_all<<<6912, 256, 0, stream>>>(qkv_w, qkvT, proj_w, projT,
                                          fc1_w, fc1T, fc2_w, fc2T);

  // dynamic position bias table [169][12] fp32
  pos_mlp_kernel<<<1, 256, 0, stream>>>(
      (const float*)d_in[13], (const float*)d_in[14], (const float*)d_in[15], (const float*)d_in[16],
      (const float*)d_in[17], (const float*)d_in[18], (const float*)d_in[19], (const float*)d_in[20],
      (const float*)d_in[21], (const float*)d_in[22], (const float*)d_in[23], (const float*)d_in[24],
      (const float*)d_in[25], (const float*)d_in[26], pos169);

  // LN1: x(fp32) -> regB(bf16)
  ln_kernel<<<TT / 4, 256, 0, stream>>>(x, n1g, n1b, regB);

  // QKV GEMM with window scatter: regB -> regA (bf16).  392x9 tiles
  gemm_k<0><<<392 * 9, 256, 0, stream>>>(regB, qkvT, qkv_b, nullptr, regA,
                                         384, 9, 0);

  // attention (MFMA): regA -> regB (attn_out bf16, token order)
  attn_mfma<<<NWIN * NH / 4, 256, 0, stream>>>(regA, pos169, regB);

  // proj + residual(x fp32): regB -> d_out (fp32 x2).  392x3 tiles
  gemm_k<1><<<392 * 3, 256, 0, stream>>>(regB, projT, proj_b, x, out,
                                         384, 3, 0);

  // LN2: d_out(fp32) -> regB(bf16)
  ln_kernel<<<TT / 4, 256, 0, stream>>>(out, n2g, n2b, regB);

  // MLP in 2 row-chunks of 25088 (hidden bf16 reuses regA)
  for (int ch = 0; ch < 2; ch++) {
    const u16* h2c = regB + (size_t)ch * 25088 * 384;
    gemm_k<2><<<196 * 12, 256, 0, stream>>>(h2c, fc1T, fc1_b, nullptr, regA,
                                            384, 12, 0);
    gemm_k<1><<<196 * 3, 256, 0, stream>>>(regA, fc2T, fc2_b, out, out,
                                           1536, 3, ch * 25088);
  }
}